// Round 1
// baseline (885.979 us; speedup 1.0000x reference)
//
#include <hip/hip_runtime.h>

#define NROWS   262144
#define HIDDEN  512
#define NGATES  64
#define NGRAPHS 1024
#define MAXR    512    // defensive clamp on rows/graph (true max ~310)
#define CH      128    // rows per chunk (8 row-tiles of 16)
#define ETS     136    // eT row stride in bf16 elems: 272 B, 16B-aligned, spreads banks
#define GPB     4      // graphs per block (256 persistent blocks, 1/CU)

typedef __attribute__((ext_vector_type(8))) short short8;
typedef __attribute__((ext_vector_type(4))) float floatx4;

__device__ __forceinline__ unsigned short f2bf(float f) {
    unsigned int u = __float_as_uint(f);
    unsigned int r = (u + 0x7fffu + ((u >> 16) & 1u)) >> 16;
    return (unsigned short)r;
}
__device__ __forceinline__ float bf2f(unsigned short u) {
    return __uint_as_float((unsigned int)u << 16);
}

// K0: relayout W [512,64] fp32 -> MFMA B-fragment layout, bf16. (unchanged)
__global__ void k_wfrag(const float* __restrict__ W, unsigned short* __restrict__ wf) {
    int tile = blockIdx.x;    // 0..63 = kstep*4 + nt
    int lane = threadIdx.x;   // 0..63
    int kstep = tile >> 2, nt = tile & 3;
    int kbase = kstep * 32 + (lane >> 4) * 8;
    int col   = nt * 16 + (lane & 15);
    unsigned short* dst = wf + ((size_t)tile * 64 + lane) * 8;
#pragma unroll
    for (int j = 0; j < 8; ++j)
        dst[j] = f2bf(W[(size_t)(kbase + j) * NGATES + col]);
}

// K1: segment boundaries via binary search over sorted batch. (unchanged)
__global__ void k_bounds(const int* __restrict__ batch, int* __restrict__ segstart) {
    int g = blockIdx.x * blockDim.x + threadIdx.x;
    if (g > NGRAPHS) return;
    if (g == NGRAPHS) { segstart[g] = NROWS; return; }
    int lo = 0, hi = NROWS;
    while (lo < hi) { int mid = (lo + hi) >> 1; if (batch[mid] < g) lo = mid + 1; else hi = mid; }
    segstart[g] = lo;
}

// K2: fused single-pass. out[g] = (1/64) * sum_k M[k]/S_k, M[k][c] = sum_i e_ik x_i[c].
// Persistent block handles 4 graphs; flat chunk list (128 rows/chunk), software
// pipeline: gate(chunk j+1) overlaps pool(chunk j); 1 barrier/chunk; eT double-buffered.
//  gate (waves 0-7): stream x from HBM, x@W via MFMA, exp -> eT[64][ETS] bf16 (transposed),
//                    per-gate partial sums via LDS atomics (ping-pong per graph parity).
//  pool (all 16 waves, 32 cols each): M += e^T @ x via MFMA; A = eT (ds_read_b128),
//                    B = x re-read as scalar fp32 from L2/L3 (chunk is cache-hot),
//                    split bf16 hi+lo so pooling precision ~fp32.
//  epilogue per graph: out[c] = (1/64) sum_k D[k][c] * 1/(S_k+eps).
__global__ __launch_bounds__(1024, 4) void k_main(const float* __restrict__ x,
                                                  const unsigned short* __restrict__ wf,
                                                  const int* __restrict__ segstart,
                                                  float* __restrict__ out) {
    __shared__ unsigned short eT[2][NGATES][ETS];   // 34816 B, double-buffered e^T
    __shared__ float sums[2][NGATES];               // ping-pong by graph parity
    __shared__ float rinv[NGATES];

    const int t = threadIdx.x;
    const int lane = t & 63, wv = t >> 6;
    const int m = lane & 15, q = lane >> 4;
    const int G0 = blockIdx.x * GPB;

    // segment info (wave-uniform)
    int sg[GPB + 1];
#pragma unroll
    for (int k = 0; k <= GPB; ++k) sg[k] = segstart[G0 + k];
    const int r0 = min(sg[1] - sg[0], MAXR), r1 = min(sg[2] - sg[1], MAXR);
    const int r2 = min(sg[3] - sg[2], MAXR), r3 = min(sg[4] - sg[3], MAXR);
    const int n0 = max(1, (r0 + CH - 1) / CH), n1 = max(1, (r1 + CH - 1) / CH);
    const int n2 = max(1, (r2 + CH - 1) / CH), n3 = max(1, (r3 + CH - 1) / CH);
    const int p1 = n0, p2 = n0 + n1, p3 = n0 + n1 + n2;
    const int nitems = n0 + n1 + n2 + n3;

    // flat item j -> (chunk base row, rows in chunk, graph parity, last-chunk flag)
    auto decode = [&](int j, int& chbase, int& chrows, int& par, bool& lastc) {
        int gi = (j >= p1) + (j >= p2) + (j >= p3);
        int pstart = gi == 0 ? 0 : (gi == 1 ? p1 : (gi == 2 ? p2 : p3));
        int sbase  = gi == 0 ? sg[0] : (gi == 1 ? sg[1] : (gi == 2 ? sg[2] : sg[3]));
        int rowsg  = gi == 0 ? r0 : (gi == 1 ? r1 : (gi == 2 ? r2 : r3));
        int nchg   = gi == 0 ? n0 : (gi == 1 ? n1 : (gi == 2 ? n2 : n3));
        int ch = j - pstart;
        chbase = sbase + ch * CH;
        chrows = min(rowsg - ch * CH, CH);
        par = gi & 1;
        lastc = (ch == nchg - 1);
    };

    const short8* wfv = (const short8*)wf;

    // ---- gate phase: compute e for chunk j, write eT[j&1], accumulate sums ----
    auto gate_phase = [&](int j) {
        if (wv >= 8) return;
        int chbase, chrows, par; bool lastc;
        decode(j, chbase, chrows, par, lastc);
        const int buf = j & 1;
        const int rloc0 = wv * 16;                       // chunk-local base row of this wave
        const int garow = chbase + rloc0 + m;
        const float* xrow = x + (size_t)min(garow, NROWS - 1) * HIDDEN + q * 8;

        floatx4 acc0 = {0.f,0.f,0.f,0.f}, acc1 = {0.f,0.f,0.f,0.f};
        floatx4 acc2 = {0.f,0.f,0.f,0.f}, acc3 = {0.f,0.f,0.f,0.f};
#pragma unroll 4
        for (int ks = 0; ks < 16; ++ks) {
            float4 a0 = *(const float4*)(xrow + ks * 32);
            float4 a1 = *(const float4*)(xrow + ks * 32 + 4);
            short8 af;
            af[0] = (short)f2bf(a0.x); af[1] = (short)f2bf(a0.y);
            af[2] = (short)f2bf(a0.z); af[3] = (short)f2bf(a0.w);
            af[4] = (short)f2bf(a1.x); af[5] = (short)f2bf(a1.y);
            af[6] = (short)f2bf(a1.z); af[7] = (short)f2bf(a1.w);
            short8 b0 = wfv[(ks * 4 + 0) * 64 + lane];
            short8 b1 = wfv[(ks * 4 + 1) * 64 + lane];
            short8 b2 = wfv[(ks * 4 + 2) * 64 + lane];
            short8 b3 = wfv[(ks * 4 + 3) * 64 + lane];
            acc0 = __builtin_amdgcn_mfma_f32_16x16x32_bf16(af, b0, acc0, 0, 0, 0);
            acc1 = __builtin_amdgcn_mfma_f32_16x16x32_bf16(af, b1, acc1, 0, 0, 0);
            acc2 = __builtin_amdgcn_mfma_f32_16x16x32_bf16(af, b2, acc2, 0, 0, 0);
            acc3 = __builtin_amdgcn_mfma_f32_16x16x32_bf16(af, b3, acc3, 0, 0, 0);
        }

        // D layout: gate = nt*16 + m, chunk-row = rloc0 + q*4 + r
        float vs0 = 0.f, vs1 = 0.f, vs2 = 0.f, vs3 = 0.f;
        unsigned short pe[4][4];
#pragma unroll
        for (int r = 0; r < 4; ++r) {
            const int rloc = rloc0 + q * 4 + r;
            const bool valid = rloc < chrows;
            const float e0 = valid ? __expf(acc0[r]) : 0.f;
            const float e1 = valid ? __expf(acc1[r]) : 0.f;
            const float e2 = valid ? __expf(acc2[r]) : 0.f;
            const float e3 = valid ? __expf(acc3[r]) : 0.f;
            pe[0][r] = f2bf(e0); pe[1][r] = f2bf(e1);
            pe[2][r] = f2bf(e2); pe[3][r] = f2bf(e3);
            vs0 += e0; vs1 += e1; vs2 += e2; vs3 += e3;
        }
        // transposed store: eT[gate][row], 4 consecutive rows -> one 8B write
#pragma unroll
        for (int nt = 0; nt < 4; ++nt) {
            ushort4 pk; pk.x = pe[nt][0]; pk.y = pe[nt][1]; pk.z = pe[nt][2]; pk.w = pe[nt][3];
            *(ushort4*)&eT[buf][nt * 16 + m][rloc0 + q * 4] = pk;
        }
        vs0 += __shfl_xor(vs0, 16, 64); vs0 += __shfl_xor(vs0, 32, 64);
        vs1 += __shfl_xor(vs1, 16, 64); vs1 += __shfl_xor(vs1, 32, 64);
        vs2 += __shfl_xor(vs2, 16, 64); vs2 += __shfl_xor(vs2, 32, 64);
        vs3 += __shfl_xor(vs3, 16, 64); vs3 += __shfl_xor(vs3, 32, 64);
        if (q == 0) {
            atomicAdd(&sums[par][m],      vs0); atomicAdd(&sums[par][m + 16], vs1);
            atomicAdd(&sums[par][m + 32], vs2); atomicAdd(&sums[par][m + 48], vs3);
        }
    };

    // ---- M accumulators: D[mt][nt] covers gates mt*16..+16 x cols wv*32+nt*16..+16 ----
    floatx4 D00={0.f,0.f,0.f,0.f}, D01={0.f,0.f,0.f,0.f}, D10={0.f,0.f,0.f,0.f}, D11={0.f,0.f,0.f,0.f};
    floatx4 D20={0.f,0.f,0.f,0.f}, D21={0.f,0.f,0.f,0.f}, D30={0.f,0.f,0.f,0.f}, D31={0.f,0.f,0.f,0.f};

    // ---- pool phase: M += e^T @ x for chunk j (x re-read from L2/L3, hi+lo bf16) ----
    auto pool_phase = [&](int j) {
        int chbase, chrows, par; bool lastc;
        decode(j, chbase, chrows, par, lastc);
        const int buf = j & 1;
        const int c0 = wv * 32;
#pragma unroll
        for (int ks2 = 0; ks2 < 4; ++ks2) {
            const int rowb = chbase + ks2 * 32 + q * 8;   // B k-rows for this lane group
            short8 bh0, bl0, bh1, bl1;
#pragma unroll
            for (int jj = 0; jj < 8; ++jj) {
                const int rr = min(rowb + jj, NROWS - 1);
                const float v0 = x[(size_t)rr * HIDDEN + c0 + m];
                const float v1 = x[(size_t)rr * HIDDEN + c0 + 16 + m];
                const unsigned short h0 = f2bf(v0);
                const unsigned short h1 = f2bf(v1);
                bh0[jj] = (short)h0; bl0[jj] = (short)f2bf(v0 - bf2f(h0));
                bh1[jj] = (short)h1; bl1[jj] = (short)f2bf(v1 - bf2f(h1));
            }
            const short8 a0 = *(const short8*)&eT[buf][ 0 + m][ks2 * 32 + q * 8];
            const short8 a1 = *(const short8*)&eT[buf][16 + m][ks2 * 32 + q * 8];
            const short8 a2 = *(const short8*)&eT[buf][32 + m][ks2 * 32 + q * 8];
            const short8 a3 = *(const short8*)&eT[buf][48 + m][ks2 * 32 + q * 8];
            D00 = __builtin_amdgcn_mfma_f32_16x16x32_bf16(a0, bh0, D00, 0, 0, 0);
            D00 = __builtin_amdgcn_mfma_f32_16x16x32_bf16(a0, bl0, D00, 0, 0, 0);
            D01 = __builtin_amdgcn_mfma_f32_16x16x32_bf16(a0, bh1, D01, 0, 0, 0);
            D01 = __builtin_amdgcn_mfma_f32_16x16x32_bf16(a0, bl1, D01, 0, 0, 0);
            D10 = __builtin_amdgcn_mfma_f32_16x16x32_bf16(a1, bh0, D10, 0, 0, 0);
            D10 = __builtin_amdgcn_mfma_f32_16x16x32_bf16(a1, bl0, D10, 0, 0, 0);
            D11 = __builtin_amdgcn_mfma_f32_16x16x32_bf16(a1, bh1, D11, 0, 0, 0);
            D11 = __builtin_amdgcn_mfma_f32_16x16x32_bf16(a1, bl1, D11, 0, 0, 0);
            D20 = __builtin_amdgcn_mfma_f32_16x16x32_bf16(a2, bh0, D20, 0, 0, 0);
            D20 = __builtin_amdgcn_mfma_f32_16x16x32_bf16(a2, bl0, D20, 0, 0, 0);
            D21 = __builtin_amdgcn_mfma_f32_16x16x32_bf16(a2, bh1, D21, 0, 0, 0);
            D21 = __builtin_amdgcn_mfma_f32_16x16x32_bf16(a2, bl1, D21, 0, 0, 0);
            D30 = __builtin_amdgcn_mfma_f32_16x16x32_bf16(a3, bh0, D30, 0, 0, 0);
            D30 = __builtin_amdgcn_mfma_f32_16x16x32_bf16(a3, bl0, D30, 0, 0, 0);
            D31 = __builtin_amdgcn_mfma_f32_16x16x32_bf16(a3, bh1, D31, 0, 0, 0);
            D31 = __builtin_amdgcn_mfma_f32_16x16x32_bf16(a3, bl1, D31, 0, 0, 0);
        }
    };

    if (t < 2 * NGATES) ((float*)sums)[t] = 0.f;
    __syncthreads();
    gate_phase(0);
    __syncthreads();

    for (int i = 0; i < nitems; ++i) {
        if (i + 1 < nitems) gate_phase(i + 1);   // stream next chunk from HBM
        pool_phase(i);                            // consume current chunk (cache-hot)

        int chbase, chrows, par; bool lastc;
        decode(i, chbase, chrows, par, lastc);
        if (lastc) {
            __syncthreads();
            if (t < NGATES) rinv[t] = 1.0f / (sums[par][t] + 1e-16f);
            __syncthreads();
            const int gi = (i >= p1) + (i >= p2) + (i >= p3);
            const int c0 = wv * 32;
            // epilogue: out[c] = (1/64) sum_gates D * rinv  (q-groups hold gate quarters)
            float cs0 = 0.f, cs1 = 0.f;
#pragma unroll
            for (int r = 0; r < 4; ++r) {
                const float rv0 = rinv[ 0 + q * 4 + r];
                const float rv1 = rinv[16 + q * 4 + r];
                const float rv2 = rinv[32 + q * 4 + r];
                const float rv3 = rinv[48 + q * 4 + r];
                cs0 += D00[r] * rv0 + D10[r] * rv1 + D20[r] * rv2 + D30[r] * rv3;
                cs1 += D01[r] * rv0 + D11[r] * rv1 + D21[r] * rv2 + D31[r] * rv3;
            }
            cs0 += __shfl_xor(cs0, 16, 64); cs0 += __shfl_xor(cs0, 32, 64);
            cs1 += __shfl_xor(cs1, 16, 64); cs1 += __shfl_xor(cs1, 32, 64);
            if (q == 0) {
                out[(size_t)(G0 + gi) * HIDDEN + c0 + m]      = cs0 * (1.0f / 64.0f);
                out[(size_t)(G0 + gi) * HIDDEN + c0 + 16 + m] = cs1 * (1.0f / 64.0f);
            }
            // reset per-graph state (gate(i+1) used the other parity bank)
            D00 = (floatx4){0.f,0.f,0.f,0.f}; D01 = (floatx4){0.f,0.f,0.f,0.f};
            D10 = (floatx4){0.f,0.f,0.f,0.f}; D11 = (floatx4){0.f,0.f,0.f,0.f};
            D20 = (floatx4){0.f,0.f,0.f,0.f}; D21 = (floatx4){0.f,0.f,0.f,0.f};
            D30 = (floatx4){0.f,0.f,0.f,0.f}; D31 = (floatx4){0.f,0.f,0.f,0.f};
            if (t < NGATES) sums[par][t] = 0.f;
        }
        __syncthreads();   // eT[i&1] reads done; gate(i+2) may overwrite it next iter
    }
}

extern "C" void kernel_launch(void* const* d_in, const int* in_sizes, int n_in,
                              void* d_out, int out_size, void* d_ws, size_t ws_size,
                              hipStream_t stream) {
    const float* x     = (const float*)d_in[0];
    const int*   batch = (const int*)d_in[1];
    const float* W     = (const float*)d_in[2];
    float* out = (float*)d_out;

    // ws layout: [0,64K) W frags bf16 | [64K,72K) segstart
    unsigned short* wfrag = (unsigned short*)d_ws;
    int* segstart = (int*)((char*)d_ws + (64 << 10));

    hipLaunchKernelGGL(k_wfrag, dim3(64), dim3(64), 0, stream, W, wfrag);
    hipLaunchKernelGGL(k_bounds, dim3(5), dim3(256), 0, stream, batch, segstart);
    hipLaunchKernelGGL(k_main, dim3(NGRAPHS / GPB), dim3(1024), 0, stream, x, wfrag, segstart, out);
}

// Round 2
// 793.519 us; speedup vs baseline: 1.1165x; 1.1165x over previous
//
#include <hip/hip_runtime.h>

#define NROWS   262144
#define HIDDEN  512
#define NGATES  64
#define NGRAPHS 1024
#define MAXR    512   // max rows/graph handled in-LDS; true max ~310 (mean 256, sd 16)

typedef __attribute__((ext_vector_type(8))) short short8;
typedef __attribute__((ext_vector_type(4))) float floatx4;

__device__ __forceinline__ unsigned short f2bf(float f) {
    unsigned int u = __float_as_uint(f);
    unsigned int r = (u + 0x7fffu + ((u >> 16) & 1u)) >> 16;
    return (unsigned short)r;
}
__device__ __forceinline__ float bf2f(unsigned short u) {
    return __uint_as_float((unsigned int)u << 16);
}
// packed f32x2 -> bf16x2 (RNE), single HW instr; low half = first operand
__device__ __forceinline__ unsigned int cvtpk(float lo, float hi) {
    unsigned int r;
    asm("v_cvt_pk_bf16_f32 %0, %1, %2" : "=v"(r) : "v"(lo), "v"(hi));
    return r;
}

// K0: relayout W [512,64] fp32 -> MFMA B-fragment layout, bf16.
__global__ void k_wfrag(const float* __restrict__ W, unsigned short* __restrict__ wf) {
    int tile = blockIdx.x;    // 0..63 = kstep*4 + nt
    int lane = threadIdx.x;   // 0..63
    int kstep = tile >> 2, nt = tile & 3;
    int kbase = kstep * 32 + (lane >> 4) * 8;
    int col   = nt * 16 + (lane & 15);
    unsigned short* dst = wf + ((size_t)tile * 64 + lane) * 8;
#pragma unroll
    for (int j = 0; j < 8; ++j)
        dst[j] = f2bf(W[(size_t)(kbase + j) * NGATES + col]);
}

// K1: segment boundaries via binary search over sorted batch.
__global__ void k_bounds(const int* __restrict__ batch, int* __restrict__ segstart) {
    int g = blockIdx.x * blockDim.x + threadIdx.x;
    if (g > NGRAPHS) return;
    if (g == NGRAPHS) { segstart[g] = NROWS; return; }
    int lo = 0, hi = NROWS;
    while (lo < hi) { int mid = (lo + hi) >> 1; if (batch[mid] < g) lo = mid + 1; else hi = mid; }
    segstart[g] = lo;
}

// K2: one block per graph, 1024 threads (16 waves).
// Phase A: gate = x@W via bf16 MFMA (tiles of 16 rows starting at s), e=exp(gate)
//          stored bf16 in LDS, per-gate sums in LDS (block-local, no global atomics).
//          A-operand pack via v_cvt_pk_bf16_f32 (4 instrs vs ~32 VALU bit-twiddle).
// Phase B1: per-row mean weight w_i from LDS e + rinv (wave shuffle-reduce).
// Phase B2: out[g] = sum_i w_i * x_i  — x slab re-read (512 KB/block, L2/L3-hot:
//          ~1-2 blocks/CU resident -> concurrent working set < 256 MB L3),
//          float4 loads (16 B/lane), 8-way row interleave.
__global__ __launch_bounds__(1024, 4) void k_main(const float* __restrict__ x,
                                                  const unsigned short* __restrict__ wf,
                                                  const int* __restrict__ segstart,
                                                  float* __restrict__ out) {
    __shared__ unsigned short eL[MAXR * NGATES];  // 64 KB; reused as red[8][512] in B2
    __shared__ float wl[MAXR];                    // 2 KB
    __shared__ float sums[NGATES];
    __shared__ float rinv[NGATES];

    const int g = blockIdx.x;
    const int t = threadIdx.x;
    const int lane = t & 63, wv = t >> 6;
    const int m = lane & 15, q = lane >> 4;
    const int s = segstart[g], e = segstart[g + 1];
    const int rows = min(e - s, MAXR);           // defensive clamp (never hit for this dist)
    const int tiles = (rows + 15) >> 4;

    if (t < NGATES) sums[t] = 0.f;
    __syncthreads();

    const short8* wfv = (const short8*)wf;
    float vs0 = 0.f, vs1 = 0.f, vs2 = 0.f, vs3 = 0.f;

    // ---- Phase A ----
    for (int tile = wv; tile < tiles; tile += 16) {
        const int garow = s + tile * 16 + m;                 // this lane's A row
        const float* xrow = x + (size_t)min(garow, NROWS - 1) * HIDDEN + q * 8;

        floatx4 acc0 = {0.f,0.f,0.f,0.f}, acc1 = {0.f,0.f,0.f,0.f};
        floatx4 acc2 = {0.f,0.f,0.f,0.f}, acc3 = {0.f,0.f,0.f,0.f};
#pragma unroll 4
        for (int ks = 0; ks < 16; ++ks) {
            float4 a0 = *(const float4*)(xrow + ks * 32);
            float4 a1 = *(const float4*)(xrow + ks * 32 + 4);
            union { short8 s; unsigned int u[4]; } af;
            af.u[0] = cvtpk(a0.x, a0.y);
            af.u[1] = cvtpk(a0.z, a0.w);
            af.u[2] = cvtpk(a1.x, a1.y);
            af.u[3] = cvtpk(a1.z, a1.w);
            short8 b0 = wfv[(ks * 4 + 0) * 64 + lane];
            short8 b1 = wfv[(ks * 4 + 1) * 64 + lane];
            short8 b2 = wfv[(ks * 4 + 2) * 64 + lane];
            short8 b3 = wfv[(ks * 4 + 3) * 64 + lane];
            acc0 = __builtin_amdgcn_mfma_f32_16x16x32_bf16(af.s, b0, acc0, 0, 0, 0);
            acc1 = __builtin_amdgcn_mfma_f32_16x16x32_bf16(af.s, b1, acc1, 0, 0, 0);
            acc2 = __builtin_amdgcn_mfma_f32_16x16x32_bf16(af.s, b2, acc2, 0, 0, 0);
            acc3 = __builtin_amdgcn_mfma_f32_16x16x32_bf16(af.s, b3, acc3, 0, 0, 0);
        }

        // D layout: col = lane&15 (gate), row = q*4 + reg (local row in tile)
        const int rl0 = tile * 16 + q * 4;
#pragma unroll
        for (int r = 0; r < 4; ++r) {
            const int rloc = rl0 + r;
            const bool valid = rloc < rows;
            const float e0 = valid ? __expf(acc0[r]) : 0.f;
            const float e1 = valid ? __expf(acc1[r]) : 0.f;
            const float e2 = valid ? __expf(acc2[r]) : 0.f;
            const float e3 = valid ? __expf(acc3[r]) : 0.f;
            if (valid) {
                unsigned short* eb = eL + rloc * NGATES + m;
                eb[ 0] = f2bf(e0); eb[16] = f2bf(e1);
                eb[32] = f2bf(e2); eb[48] = f2bf(e3);
            }
            vs0 += e0; vs1 += e1; vs2 += e2; vs3 += e3;
        }
    }
    // fold the 4 q-groups, then one LDS atomic per gate per wave
    vs0 += __shfl_xor(vs0, 16, 64); vs0 += __shfl_xor(vs0, 32, 64);
    vs1 += __shfl_xor(vs1, 16, 64); vs1 += __shfl_xor(vs1, 32, 64);
    vs2 += __shfl_xor(vs2, 16, 64); vs2 += __shfl_xor(vs2, 32, 64);
    vs3 += __shfl_xor(vs3, 16, 64); vs3 += __shfl_xor(vs3, 32, 64);
    if (q == 0) {
        atomicAdd(&sums[m],      vs0); atomicAdd(&sums[m + 16], vs1);
        atomicAdd(&sums[m + 32], vs2); atomicAdd(&sums[m + 48], vs3);
    }
    __syncthreads();
    if (t < NGATES) rinv[t] = 1.0f / (sums[t] + 1e-16f);
    __syncthreads();

    // ---- Phase B1: per-row weights (lane = gate) ----
    const float rk = rinv[lane];
    const int nrq = (rows + 3) >> 2;
    for (int i4 = wv; i4 < nrq; i4 += 16) {
        const int rb = i4 * 4;
        float v0 = bf2f(eL[(rb + 0) * NGATES + lane]) * rk;
        float v1 = bf2f(eL[(rb + 1) * NGATES + lane]) * rk;
        float v2 = bf2f(eL[(rb + 2) * NGATES + lane]) * rk;
        float v3 = bf2f(eL[(rb + 3) * NGATES + lane]) * rk;
#pragma unroll
        for (int off = 1; off < 64; off <<= 1) {
            v0 += __shfl_xor(v0, off, 64);
            v1 += __shfl_xor(v1, off, 64);
            v2 += __shfl_xor(v2, off, 64);
            v3 += __shfl_xor(v3, off, 64);
        }
        if (lane == 0) {
            wl[rb + 0] = v0 * (1.0f / 64.0f); wl[rb + 1] = v1 * (1.0f / 64.0f);
            wl[rb + 2] = v2 * (1.0f / 64.0f); wl[rb + 3] = v3 * (1.0f / 64.0f);
        }
    }
    __syncthreads();   // wl visible; eL reads done -> safe to reuse as red

    // ---- Phase B2: weighted pooling, x slab re-read (float4, 8-way interleave) ----
    const int h4 = (t & 127) * 4;
    const int p = t >> 7;   // 0..7 row-interleave group
    float ax = 0.f, ay = 0.f, az = 0.f, aw = 0.f;
#pragma unroll 4
    for (int i = p; i < rows; i += 8) {
        const float w = wl[i];
        const float4 xv = *(const float4*)(x + (size_t)(s + i) * HIDDEN + h4);
        ax = fmaf(w, xv.x, ax);
        ay = fmaf(w, xv.y, ay);
        az = fmaf(w, xv.z, az);
        aw = fmaf(w, xv.w, aw);
    }
    float* red = (float*)eL;      // 8 * 512 floats = 16 KB
    float4 st; st.x = ax; st.y = ay; st.z = az; st.w = aw;
    *(float4*)&red[p * 512 + h4] = st;
    __syncthreads();
    if (p == 0) {
        float4 o = *(const float4*)&red[h4];
#pragma unroll
        for (int k = 1; k < 8; ++k) {
            const float4 v = *(const float4*)&red[k * 512 + h4];
            o.x += v.x; o.y += v.y; o.z += v.z; o.w += v.w;
        }
        *(float4*)(out + (size_t)g * HIDDEN + h4) = o;
    }
}

extern "C" void kernel_launch(void* const* d_in, const int* in_sizes, int n_in,
                              void* d_out, int out_size, void* d_ws, size_t ws_size,
                              hipStream_t stream) {
    const float* x     = (const float*)d_in[0];
    const int*   batch = (const int*)d_in[1];
    const float* W     = (const float*)d_in[2];
    float* out = (float*)d_out;

    // ws layout: [0,64K) W frags bf16 | [64K,72K) segstart
    unsigned short* wfrag = (unsigned short*)d_ws;
    int* segstart = (int*)((char*)d_ws + (64 << 10));

    hipLaunchKernelGGL(k_wfrag, dim3(64), dim3(64), 0, stream, W, wfrag);
    hipLaunchKernelGGL(k_bounds, dim3(5), dim3(256), 0, stream, batch, segstart);
    hipLaunchKernelGGL(k_main, dim3(NGRAPHS), dim3(1024), 0, stream, x, wfrag, segstart, out);
}